// Round 28
// baseline (128.418 us; speedup 1.0000x reference)
//
#include <hip/hip_runtime.h>
#include <hip/hip_fp16.h>

typedef __attribute__((ext_vector_type(8))) _Float16 half8;
typedef __attribute__((ext_vector_type(2))) _Float16 h2f;
typedef __attribute__((ext_vector_type(4))) float f32x4;

#define NP 1369
#define KP 1376          /* padded row stride: 43 tiles of 32 */
#define NKT 43
#define ROWS_A 15360     /* 768 sbk * 20 t  */
#define ROWS_D 14592     /* 768 sbk * 19 dt */

/* ws layout (ushort units). total = 84,119,488 B <= 84.25MB proven */
#define PA_OFF   0
#define PD_OFF   (ROWS_A * KP)          /* Hraw fp32 (gemm); PDIG fp16 (k0->k1a, aliased) */
#define PWH_OFF  (PD_OFF + ROWS_D * KP)
#define PWD_OFF  (PWH_OFF + NKT * 16 * 512)
#define PW2_OFF  (PWD_OFF + NKT * 16 * 512)
#define PWD2_OFF (PW2_OFF + 8 * 16 * 512)
#define TSUM_OFF (PWD2_OFF + 8 * 8 * 512)   /* 768 floats */

/* k1a frame-copy layout (dwords): copy0 at 0, copy1 at 2384 (== 16 mod 32 banks) */
#define SHIFT_DW 2384

__device__ __forceinline__ unsigned short f2h(float f) {
    __half h = __float2half(f);
    return __half_as_ushort(h);
}
__device__ __forceinline__ h2f u2h2(unsigned int u) {
    h2f r; __builtin_memcpy(&r, &u, 4); return r;
}

// ============ k0: pack weights (fp16 B-frags) + tsum + PDIG template pack ============
__global__ __launch_bounds__(256)
void k0_pack(const float* __restrict__ w_h1, const float* __restrict__ wd1,
             const float* __restrict__ wm1,  const float* __restrict__ ws1,
             const float* __restrict__ wd2,  const float* __restrict__ digit,
             unsigned short* __restrict__ wsu, float* __restrict__ tsum)
{
    const int tid = threadIdx.x;
    if (blockIdx.x >= 3328) {            // PDIG pack: 86016 uint4s
        int g = (blockIdx.x - 3328) * 256 + tid;   // 0..86015
        int sbk = g / 112;
        int rem = g - sbk * 112;
        int kt = rem >> 2, v0g = rem & 3;
        const float* tp = digit + (size_t)sbk * 784 + kt * 28 + v0g * 8;
        float4 fa = *(const float4*)tp;
        float4 fb = (v0g < 3) ? *(const float4*)(tp + 4) : make_float4(0.f, 0.f, 0.f, 0.f);
        uint4 pk;
        pk.x = (unsigned)f2h(fa.x) | ((unsigned)f2h(fa.y) << 16);
        pk.y = (unsigned)f2h(fa.z) | ((unsigned)f2h(fa.w) << 16);
        pk.z = (unsigned)f2h(fb.x) | ((unsigned)f2h(fb.y) << 16);
        pk.w = (unsigned)f2h(fb.z) | ((unsigned)f2h(fb.w) << 16);
        *(uint4*)(wsu + PD_OFF + (size_t)g * 8) = pk;
        return;
    }
    if (blockIdx.x >= 3136) {            // tsum blocks: 4 sbk per block
        const int sbk = (blockIdx.x - 3136) * 4 + (tid >> 6);
        const int l = tid & 63;
        const float* tp = digit + (size_t)sbk * 784;
        float s = 0.f;
        for (int i = l; i < 784; i += 64) s += tp[i];
        for (int o = 32; o; o >>= 1) s += __shfl_xor(s, o, 64);
        if (l == 0) tsum[sbk] = 0.5f * s;
        return;
    }
    int idx = blockIdx.x * 256 + tid;      // 0..802815
    int local, mode;
    unsigned short* dst;
    if (idx < 352256)      { mode = 0; local = idx;          dst = wsu + PWH_OFF; }
    else if (idx < 704512) { mode = 1; local = idx - 352256; dst = wsu + PWD_OFF; }
    else if (idx < 770048) { mode = 2; local = idx - 704512; dst = wsu + PW2_OFF; }
    else                   { mode = 3; local = idx - 770048; dst = wsu + PWD2_OFF; }
    int j = local & 7, lane = (local >> 3) & 63, rest = local >> 9;
    int NTn = (mode == 3) ? 8 : 16;
    int nt = rest % NTn, kt = rest / NTn;
    int k = kt * 32 + ((lane >> 4) << 3) + j;
    int n = nt * 16 + (lane & 15);
    float v = 0.f;
    if (mode == 0)      { if (k < NP) v = w_h1[k * 256 + n]; }
    else if (mode == 1) { if (k < NP) v = wd1[k * 256 + n]; }
    else if (mode == 2) { v = (n < 128) ? wm1[k * 128 + n] : ws1[k * 128 + (n - 128)]; }
    else                { v = wd2[k * 128 + n]; }
    dst[local] = f2h(v);
}

// ============ k1a: im2col MFMA correlation, N=48, 4-phase B (PDIG copy), dual frame copy ==
__global__ __launch_bounds__(512)
void k1a_corr(const float* __restrict__ frames, const float* __restrict__ digit,
              const float* __restrict__ tsum, unsigned short* __restrict__ wsu)
{
    __shared__ __align__(16) unsigned short Bs[7 * 3 * 512];   // 21,504 B; TT alias 13,056 B
    __shared__ __align__(16) unsigned int frd[SHIFT_DW + 64 * 37];  // 19,008 B
    __shared__ float Cn[48];

    const int tid = threadIdx.x, l = tid & 63, w = tid >> 6;
    const int mh = blockIdx.x & 1;
    const int bt = blockIdx.x >> 1;
    const int t  = bt % 20;
    const int bb = bt / 20;
    const unsigned short* pdig = wsu + PD_OFF;

    if (tid < 48) {
        int sbk_n = ((tid / 3) * 16 + bb) * 3 + (tid % 3);
        Cn[tid] = tsum[sbk_n];
    }
    if (tid < 320) {   // zero pad dwords 32..36 of both copies
        int r = tid / 5, d2 = tid - r * 5;
        frd[r * 37 + 32 + d2] = 0u;
        frd[SHIFT_DW + r * 37 + 32 + d2] = 0u;
    }
    {   // stage aligned fp16-pair copy (scalar dword stores; odd stride)
        const float4* fp4 = (const float4*)(frames + (size_t)(bb * 20 + t) * 4096);
        for (int idx = tid; idx < 1024; idx += 512) {
            float4 v = fp4[idx];
            int r = idx >> 4, c4 = idx & 15;
            unsigned lo = (unsigned)f2h(v.x) | ((unsigned)f2h(v.y) << 16);
            unsigned hi = (unsigned)f2h(v.z) | ((unsigned)f2h(v.w) << 16);
            frd[r * 37 + c4 * 2]     = lo;
            frd[r * 37 + c4 * 2 + 1] = hi;
        }
    }
    __syncthreads();
    // build shifted copy: dword d holds halfs (2d+1, 2d+2)
    for (int i = tid; i < 64 * 34; i += 512) {
        int r = i / 34, d = i - r * 34;
        unsigned lo = frd[r * 37 + d], hi = frd[r * 37 + d + 1];
        frd[SHIFT_DW + r * 37 + d] = (lo >> 16) | (hi << 16);
    }

    const int c15 = l & 15, quad = l >> 4, v0q = quad << 3;
    const int cnt = (50 - w) / 8;        // waves 0-2: 6 tiles, 3-7: 5 tiles (43 total)

    int baseb[6];
#pragma unroll
    for (int it = 0; it < 6; ++it) {
        int tI = mh * 43 + w + 8 * it;
        int p  = tI * 16 + c15;
        int pc = p > 1368 ? 1368 : p;
        int i  = pc / 37;
        int jj = pc - i * 37;
        int c  = jj + v0q;
        baseb[it] = (c & 1) * (SHIFT_DW * 4) + i * 148 + ((c >> 1) << 2);   // byte offset
    }
    f32x4 acc[6][3];
#pragma unroll
    for (int it = 0; it < 6; ++it)
#pragma unroll
        for (int nt = 0; nt < 3; ++nt) acc[it][nt] = (f32x4){0.f, 0.f, 0.f, 0.f};

    for (int ph = 0; ph < 4; ++ph) {
        __syncthreads();   // frd ready (ph0); Bs consumers done (ph>0)
        // ---- stage B for kt = ph*7 .. ph*7+6 (uint4 copy from PDIG) ----
        for (int s = tid; s < 1344; s += 512) {
            int ktl = s / 192;
            int rem = s - ktl * 192;
            int nt = rem >> 6, sl = rem & 63;
            int nl = nt * 16 + (sl & 15);
            int kt = ph * 7 + ktl;
            int sbk_n = ((nl / 3) * 16 + bb) * 3 + (nl % 3);
            uint4 pk = *(const uint4*)(pdig + (size_t)sbk_n * 896 + kt * 32 + (sl >> 4) * 8);
            *(uint4*)(Bs + s * 8) = pk;
        }
        __syncthreads();

        for (int ktl = 0; ktl < 7; ++ktl) {
            const int kt = ph * 7 + ktl;
            half8 bf0 = *(const half8*)(Bs + ktl * 1536 + 0 * 512 + l * 8);
            half8 bf1 = *(const half8*)(Bs + ktl * 1536 + 1 * 512 + l * 8);
            half8 bf2 = *(const half8*)(Bs + ktl * 1536 + 2 * 512 + l * 8);
            const char* fb2 = (const char*)frd + (size_t)kt * 148;
#pragma unroll
            for (int it = 0; it < 6; ++it) {
                if (it < cnt) {
                    const unsigned* ap = (const unsigned*)(fb2 + baseb[it]);
                    union { unsigned u[4]; half8 h8; } af;
                    af.u[0] = ap[0];
                    af.u[1] = ap[1];
                    af.u[2] = ap[2];
                    af.u[3] = ap[3];
                    acc[it][0] = __builtin_amdgcn_mfma_f32_16x16x32_f16(af.h8, bf0, acc[it][0], 0, 0, 0);
                    acc[it][1] = __builtin_amdgcn_mfma_f32_16x16x32_f16(af.h8, bf1, acc[it][1], 0, 0, 0);
                    acc[it][2] = __builtin_amdgcn_mfma_f32_16x16x32_f16(af.h8, bf2, acc[it][2], 0, 0, 0);
                }
            }
        }
    }

    // ---- epilogue: per it-group, LDS transpose (TT=Bs alias) -> coalesced writes ----
    for (int itg = 0; itg < 6; ++itg) {
        __syncthreads();   // previous itg copy (or main-loop Bs reads) done
        if (itg < cnt) {
#pragma unroll
            for (int nt = 0; nt < 3; ++nt) {
                const int nl = nt * 16 + c15;
                const float C = Cn[nl];
                ushort4 st;
                st.x = f2h(acc[itg][nt][0] - C);
                st.y = f2h(acc[itg][nt][1] - C);
                st.z = f2h(acc[itg][nt][2] - C);
                st.w = f2h(acc[itg][nt][3] - C);
                *(ushort4*)(Bs + nl * 136 + w * 16 + quad * 4) = st;
            }
        }
        __syncthreads();
        const int nseg = (itg == 5) ? 6 : 16;   // 8-half segments per row
        for (int i = tid; i < 48 * nseg; i += 512) {
            int rowl = i / nseg, seg = i - rowl * nseg;
            int sbk_n = ((rowl / 3) * 16 + bb) * 3 + (rowl % 3);
            uint4 v = *(const uint4*)(Bs + rowl * 136 + seg * 8);
            *(uint4*)(wsu + PA_OFF + (size_t)(sbk_n * 20 + t) * KP
                      + mh * 688 + itg * 128 + seg * 8) = v;
        }
    }
}

// ============ k2_gemm: H-blocks (0..239) and D-blocks (240..479), 256 thr ============
// H: softmax@w_h1 -> hidden (LDS) -> fused mid+head -> q_mean/q_std out.
// D: raw@wd1 -> Hraw global. 2 blocks/CU -> cross-block latency hiding.
__global__ __launch_bounds__(256)
void k2_gemm(unsigned short* __restrict__ wsu, const float* __restrict__ b_h1,
             const float* __restrict__ bm1, const float* __restrict__ bs1,
             const float* __restrict__ wm2, const float* __restrict__ bm2,
             const float* __restrict__ ws2, const float* __restrict__ bs2,
             float* __restrict__ out)
{
    __shared__ __align__(16) unsigned short Bbuf[2][8192];   // 32KB
    __shared__ __align__(16) unsigned short Hs[64 * 264];    // 33.8KB (H only)
    __shared__ float2 smstats[64];

    const int tid = threadIdx.x, l = tid & 63, w = tid >> 6;   // w in 0..3
    const int c15 = l & 15, quad = l >> 4;
    const bool isH = (blockIdx.x < 240);
    const int M0 = (isH ? blockIdx.x : blockIdx.x - 240) * 64;
    unsigned short* Abase = wsu + PA_OFF;
    const unsigned short* PW1 = wsu + (isH ? PWH_OFF : PWD_OFF);
    float* HR = (float*)(wsu + PD_OFF);

    const int row0 = M0 + w * 16 + c15;
    const unsigned short* a0p = Abase + (size_t)row0 * KP + quad * 8;

    if (isH) {
        // ---- stats prepass: wave w handles local rows w*16 .. w*16+15 ----
        for (int rr = 0; rr < 16; ++rr) {
            const int lrow = w * 16 + rr;
            const unsigned* rp = (const unsigned*)(Abase + (size_t)(M0 + lrow) * KP);
            float f0[11], f1[11];
            float mx = -3.0e38f;
#pragma unroll
            for (int i = 0; i < 11; ++i) {
                int q = l + i * 64;
                unsigned u = (q < 685) ? rp[q] : 0u;
                h2f h = u2h2(u);
                f0[i] = (q < 685) ? (float)h[0] : -3.0e38f;
                f1[i] = (q < 684) ? (float)h[1] : -3.0e38f;   // half 1369 is pad
                mx = fmaxf(mx, fmaxf(f0[i], f1[i]));
            }
            for (int o = 32; o; o >>= 1) mx = fmaxf(mx, __shfl_xor(mx, o, 64));
            float sum = 0.f;
#pragma unroll
            for (int i = 0; i < 11; ++i)
                sum += __expf(f0[i] - mx) + __expf(f1[i] - mx);
            for (int o = 32; o; o >>= 1) sum += __shfl_xor(sum, o, 64);
            if (l == 0) smstats[lrow] = make_float2(mx, 1.0f / sum);
        }
    }

    f32x4 acc[16];
#pragma unroll
    for (int n = 0; n < 16; ++n) acc[n] = (f32x4){0.f, 0.f, 0.f, 0.f};

    // prologue: stage B(0) -> buf0 (4 int4/thread); load A(0)
    {
        const int4* src = (const int4*)(PW1);
        int4* dst = (int4*)(Bbuf[0]);
#pragma unroll
        for (int c = 0; c < 4; ++c) dst[tid + 256 * c] = src[tid + 256 * c];
    }
    half8 curA = *(const half8*)(a0p);
    __syncthreads();   // smstats + Bbuf[0] ready

    float2 st0 = make_float2(0.f, 0.f);
    if (isH) st0 = smstats[w * 16 + c15];

    for (int kt = 0; kt < NKT; ++kt) {
        const int db = kt & 1;
        half8 nxtA = curA;
        if (kt + 1 < NKT) nxtA = *(const half8*)(a0p + (kt + 1) * 32);
        int4 rB[4];
        if (kt + 1 < NKT) {
            const int4* src = (const int4*)(PW1 + (size_t)(kt + 1) * 8192);
#pragma unroll
            for (int c = 0; c < 4; ++c) rB[c] = src[tid + 256 * c];
        }
        half8 af = curA;
        if (isH) {
            union { half8 h8; unsigned u[4]; } ia, oa;
            ia.h8 = af;
#pragma unroll
            for (int q = 0; q < 4; ++q) {
                h2f ha = u2h2(ia.u[q]);
                float a0 = __expf((float)ha[0] - st0.x) * st0.y;
                float a1 = __expf((float)ha[1] - st0.x) * st0.y;
                oa.u[q] = (unsigned)f2h(a0) | ((unsigned)f2h(a1) << 16);
            }
            af = oa.h8;
        }
#pragma unroll
        for (int nt = 0; nt < 16; ++nt) {
            half8 bf = *(const half8*)(Bbuf[db] + nt * 512 + l * 8);
            acc[nt] = __builtin_amdgcn_mfma_f32_16x16x32_f16(af, bf, acc[nt], 0, 0, 0);
        }
        if (kt + 1 < NKT) {
            int4* dst = (int4*)(Bbuf[db ^ 1]);
#pragma unroll
            for (int c = 0; c < 4; ++c) dst[tid + 256 * c] = rB[c];
        }
        curA = nxtA;
        __syncthreads();
    }

    if (!isH) {
        // ---- D epilogue: Hraw fp32 -> global; done ----
#pragma unroll
        for (int nt = 0; nt < 16; ++nt) {
            const int col = nt * 16 + c15;
#pragma unroll
            for (int r = 0; r < 4; ++r) {
                const int row = M0 + w * 16 + quad * 4 + r;
                HR[(size_t)row * 256 + col] = acc[nt][r];
            }
        }
        return;
    }

    // ---- H epilogue: hidden -> Hs (swizzled) ----
#pragma unroll
    for (int nt = 0; nt < 16; ++nt) {
        const int col = nt * 16 + c15;
        const float bv = b_h1[col];
#pragma unroll
        for (int r = 0; r < 4; ++r) {
            const int lrow = w * 16 + quad * 4 + r;
            const int csw = col ^ ((lrow & 7) << 3);
            float v = acc[nt][r] + bv;
            Hs[lrow * 264 + csw] = f2h(v > 0.f ? v : 0.f);
        }
    }
    __syncthreads();   // Hs visible to head phase

    // ===== fused heads: 4 waves, wave w owns tile w, full N=256 =====
    const unsigned short* PW2 = wsu + PW2_OFF;
    {
        const int4* src = (const int4*)(PW2);
        int4* dst = (int4*)(Bbuf[0]);
#pragma unroll
        for (int cc = 0; cc < 4; ++cc) dst[tid + 256 * cc] = src[tid + 256 * cc];
    }
    __syncthreads();

    f32x4 acc2[16];
#pragma unroll
    for (int n = 0; n < 16; ++n) acc2[n] = (f32x4){0.f, 0.f, 0.f, 0.f};

    const int hr0 = w * 16 + c15;
    for (int kt = 0; kt < 8; ++kt) {
        const int db = kt & 1;
        int4 rB2[4];
        if (kt + 1 < 8) {
            const int4* src = (const int4*)(PW2 + (size_t)(kt + 1) * 8192);
#pragma unroll
            for (int cc = 0; cc < 4; ++cc) rB2[cc] = src[tid + 256 * cc];
        }
        {
            const int hoff = (kt * 32 + quad * 8) ^ ((hr0 & 7) << 3);
            half8 af2 = *(const half8*)(Hs + hr0 * 264 + hoff);
#pragma unroll
            for (int nt = 0; nt < 16; ++nt) {
                half8 bf = *(const half8*)(Bbuf[db] + nt * 512 + l * 8);
                acc2[nt] = __builtin_amdgcn_mfma_f32_16x16x32_f16(af2, bf, acc2[nt], 0, 0, 0);
            }
        }
        if (kt + 1 < 8) {
            int4* dst = (int4*)(Bbuf[db ^ 1]);
#pragma unroll
            for (int cc = 0; cc < 4; ++cc) dst[tid + 256 * cc] = rB2[cc];
        }
        __syncthreads();
    }

    {
#pragma unroll
        for (int nt = 0; nt < 16; ++nt) {
            float bv = (nt < 8) ? bm1[nt * 16 + c15] : bs1[(nt - 8) * 16 + c15];
#pragma unroll
            for (int r = 0; r < 4; ++r) {
                float v = acc2[nt][r] + bv;
                acc2[nt][r] = v > 0.f ? v : 0.f;
            }
        }
        float pm[2][4], ps[2][4];
#pragma unroll
        for (int d = 0; d < 2; ++d)
#pragma unroll
            for (int r = 0; r < 4; ++r) { pm[d][r] = 0.f; ps[d][r] = 0.f; }
#pragma unroll
        for (int d = 0; d < 2; ++d)
#pragma unroll
            for (int nt = 0; nt < 8; ++nt) {
                const float wmv = wm2[(nt * 16 + c15) * 2 + d];
                const float wsv = ws2[(nt * 16 + c15) * 2 + d];
#pragma unroll
                for (int r = 0; r < 4; ++r) {
                    pm[d][r] = fmaf(acc2[nt][r], wmv, pm[d][r]);
                    ps[d][r] = fmaf(acc2[nt + 8][r], wsv, ps[d][r]);
                }
            }
#pragma unroll
        for (int o = 1; o < 16; o <<= 1)
#pragma unroll
            for (int d = 0; d < 2; ++d)
#pragma unroll
                for (int r = 0; r < 4; ++r) {
                    pm[d][r] += __shfl_xor(pm[d][r], o, 64);
                    ps[d][r] += __shfl_xor(ps[d][r], o, 64);
                }
        if (c15 == 0) {
#pragma unroll
            for (int r = 0; r < 4; ++r) {
                const int orow = M0 + w * 16 + quad * 4 + r;
                const int sbk = orow / 20, t = orow % 20;
                const int sb = sbk / 3, kk = sbk % 3;
                const int oi = ((sb * 20 + t) * 3 + kk) * 2;
                out[oi + 0] = tanhf(pm[0][r] + bm2[0]);
                out[oi + 1] = tanhf(pm[1][r] + bm2[1]);
                out[30720 + oi + 0] = __expf(ps[0][r] + bs2[0]);
                out[30720 + oi + 1] = __expf(ps[1][r] + bs2[1]);
            }
        }
    }
}

// ============ k2_heads: D-path second GEMM (K=256) + disp head ============
template <bool PATHA>
__global__ __launch_bounds__(256)
void k2_heads(unsigned short* __restrict__ wsu,
              const float* __restrict__ b1a, const float* __restrict__ b1b,
              const float* __restrict__ w2a, const float* __restrict__ b2a,
              const float* __restrict__ w2b, const float* __restrict__ b2b,
              const float* __restrict__ bd1, float* __restrict__ out)
{
    constexpr int NT2 = PATHA ? 16 : 8;
    constexpr int NI4 = NT2 / 4;
    __shared__ __align__(16) unsigned short Bsh[2][NT2 * 512];
    const int tid = threadIdx.x, l = tid & 63, w = tid >> 6;
    const int c = l & 15, quad = l >> 4;
    const int M0 = blockIdx.x * 64;
    const unsigned short* PW = wsu + (PATHA ? PW2_OFF : PWD2_OFF);

    f32x4 acc[NT2];
#pragma unroll
    for (int n = 0; n < NT2; ++n) acc[n] = (f32x4){0.f, 0.f, 0.f, 0.f};

    const int row = M0 + w * 16 + c;
    const unsigned short* arow = nullptr;
    const float* h1p = nullptr; const float* h0p = nullptr;
    if (PATHA) {
        arow = wsu + PA_OFF + (size_t)row * KP + quad * 8;
    } else {
        const float* HR = (const float*)(wsu + PD_OFF);
        const int sbk = row / 19, dt = row % 19;
        h0p = HR + (size_t)(sbk * 20 + dt) * 256 + quad * 8;
        h1p = h0p + 256;
    }

    {
        const int4* src = (const int4*)(PW);
        int4* dst = (int4*)Bsh[0];
#pragma unroll
        for (int cc = 0; cc < NI4; ++cc)
            dst[tid + 256 * cc] = src[tid + 256 * cc];
    }
    half8 curPA = {};
    float4 c1a = {}, c1b = {}, c0a = {}, c0b = {};
    if (PATHA) {
        curPA = *(const half8*)(arow);
    } else {
        c1a = *(const float4*)(h1p); c1b = *(const float4*)(h1p + 4);
        c0a = *(const float4*)(h0p); c0b = *(const float4*)(h0p + 4);
    }
    __syncthreads();

    for (int kt = 0; kt < 8; ++kt) {
        const int db = kt & 1;
        half8 nxtPA = curPA;
        float4 n1a = c1a, n1b = c1b, n0a = c0a, n0b = c0b;
        if (kt + 1 < 8) {
            if (PATHA) {
                nxtPA = *(const half8*)(arow + (kt + 1) * 32);
            } else {
                n1a = *(const float4*)(h1p + (kt + 1) * 32);
                n1b = *(const float4*)(h1p + (kt + 1) * 32 + 4);
                n0a = *(const float4*)(h0p + (kt + 1) * 32);
                n0b = *(const float4*)(h0p + (kt + 1) * 32 + 4);
            }
        }
        int4 rB[NI4];
        if (kt + 1 < 8) {
            const int4* src = (const int4*)(PW + (size_t)(kt + 1) * (NT2 * 512));
#pragma unroll
            for (int cc = 0; cc < NI4; ++cc) rB[cc] = src[tid + 256 * cc];
        }
        half8 af;
        if (PATHA) {
            af = curPA;
        } else {
            float4 bb = *(const float4*)(bd1 + kt * 32 + quad * 8);
            float4 bb2 = *(const float4*)(bd1 + kt * 32 + quad * 8 + 4);
            float v0 = fmaxf(c1a.x - c0a.x + bb.x, 0.f);
            float v1 = fmaxf(c1a.y - c0a.y + bb.y, 0.f);
            float v2 = fmaxf(c1a.z - c0a.z + bb.z, 0.f);
            float v3 = fmaxf(c1a.w - c0a.w + bb.w, 0.f);
            float v4 = fmaxf(c1b.x - c0b.x + bb2.x, 0.f);
            float v5 = fmaxf(c1b.y - c0b.y + bb2.y, 0.f);
            float v6 = fmaxf(c1b.z - c0b.z + bb2.z, 0.f);
            float v7 = fmaxf(c1b.w - c0b.w + bb2.w, 0.f);
            union { unsigned u[4]; half8 h8; } pk;
            pk.u[0] = (unsigned)f2h(v0) | ((unsigned)f2h(v1) << 16);
            pk.u[1] = (unsigned)f2h(v2) | ((unsigned)f2h(v3) << 16);
            pk.u[2] = (unsigned)f2h(v4) | ((unsigned)f2h(v5) << 16);
            pk.u[3] = (unsigned)f2h(v6) | ((unsigned)f2h(v7) << 16);
            af = pk.h8;
        }
#pragma unroll
        for (int nt = 0; nt < NT2; ++nt) {
            half8 bf = *(const half8*)(Bsh[db] + nt * 512 + l * 8);
            acc[nt] = __builtin_amdgcn_mfma_f32_16x16x32_f16(af, bf, acc[nt], 0, 0, 0);
        }
        if (kt + 1 < 8) {
            int4* dst = (int4*)Bsh[db ^ 1];
#pragma unroll
            for (int cc = 0; cc < NI4; ++cc) dst[tid + 256 * cc] = rB[cc];
        }
        curPA = nxtPA;
        c1a = n1a; c1b = n1b; c0a = n0a; c0b = n0b;
        __syncthreads();
    }
#pragma unroll
    for (int nt = 0; nt < NT2; ++nt) {
        float bv;
        if (PATHA) bv = (nt < 8) ? b1a[nt * 16 + c] : b1b[(nt - 8) * 16 + c];
        else       bv = b1a[nt * 16 + c];
#pragma unroll
        for (int r = 0; r < 4; ++r) {
            float v = acc[nt][r] + bv;
            acc[nt][r] = v > 0.f ? v : 0.f;
        }
    }
    float pm[2][4], ps[2][4];
#pragma unroll
    for (int d = 0; d < 2; ++d)
#pragma unroll
        for (int r = 0; r < 4; ++r) { pm[d][r] = 0.f; ps[d][r] = 0.f; }
#pragma unroll
    for (int d = 0; d < 2; ++d)
#pragma unroll
        for (int nt = 0; nt < 8; ++nt) {
            const float wmv = w2a[(nt * 16 + c) * 2 + d];
            float wsv = 0.f;
            if (PATHA) wsv = w2b[(nt * 16 + c) * 2 + d];
#pragma unroll
            for (int r = 0; r < 4; ++r) {
                pm[d][r] = fmaf(acc[nt][r], wmv, pm[d][r]);
                if (PATHA) ps[d][r] = fmaf(acc[nt + 8][r], wsv, ps[d][r]);
            }
        }
#pragma unroll
    for (int o = 1; o < 16; o <<= 1)
#pragma unroll
        for (int d = 0; d < 2; ++d)
#pragma unroll
            for (int r = 0; r < 4; ++r) {
                pm[d][r] += __shfl_xor(pm[d][r], o, 64);
                if (PATHA) ps[d][r] += __shfl_xor(ps[d][r], o, 64);
            }
    if (c == 0) {
#pragma unroll
        for (int r = 0; r < 4; ++r) {
            const int orow = M0 + w * 16 + quad * 4 + r;
            if (PATHA) {
                const int sbk = orow / 20, t = orow % 20;
                const int sb = sbk / 3, kk = sbk % 3;
                const int oi = ((sb * 20 + t) * 3 + kk) * 2;
                out[oi + 0] = tanhf(pm[0][r] + b2a[0]);
                out[oi + 1] = tanhf(pm[1][r] + b2a[1]);
                out[30720 + oi + 0] = __expf(ps[0][r] + b2b[0]);
                out[30720 + oi + 1] = __expf(ps[1][r] + b2b[1]);
            } else {
                const int sbk = orow / 19, dt = orow % 19;
                const int sb = sbk / 3, kk = sbk % 3;
                const int oi = 61440 + ((sb * 19 + dt) * 3 + kk) * 2;
                out[oi + 0] = tanhf(pm[0][r] + b2a[0]);
                out[oi + 1] = tanhf(pm[1][r] + b2a[1]);
            }
        }
    }
}

extern "C" void kernel_launch(void* const* d_in, const int* in_sizes, int n_in,
                              void* d_out, int out_size, void* d_ws, size_t ws_size,
                              hipStream_t stream) {
    const float* frames = (const float*)d_in[0];
    const float* digit  = (const float*)d_in[1];
    const float* w_h1   = (const float*)d_in[2];
    const float* b_h1   = (const float*)d_in[3];
    const float* wm1    = (const float*)d_in[4];
    const float* bm1    = (const float*)d_in[5];
    const float* wm2    = (const float*)d_in[6];
    const float* bm2    = (const float*)d_in[7];
    const float* ws1    = (const float*)d_in[8];
    const float* bs1    = (const float*)d_in[9];
    const float* ws2    = (const float*)d_in[10];
    const float* bs2    = (const float*)d_in[11];
    const float* wd1    = (const float*)d_in[12];
    const float* bd1    = (const float*)d_in[13];
    const float* wd2    = (const float*)d_in[14];
    const float* bd2    = (const float*)d_in[15];
    const float* wd3    = (const float*)d_in[16];
    const float* bd3    = (const float*)d_in[17];

    unsigned short* wsu = (unsigned short*)d_ws;
    float* tsum = (float*)(wsu + TSUM_OFF);
    float* o = (float*)d_out;

    k0_pack<<<dim3(3664), dim3(256), 0, stream>>>(w_h1, wd1, wm1, ws1, wd2, digit, wsu, tsum);
    k1a_corr<<<dim3(640), dim3(512), 0, stream>>>(frames, digit, tsum, wsu);
    k2_gemm<<<dim3(480), dim3(256), 0, stream>>>(wsu, b_h1, bm1, bs1, wm2, bm2, ws2, bs2, o);
    k2_heads<false><<<dim3(228), dim3(256), 0, stream>>>(wsu, bd2, nullptr, wd3, bd3, nullptr, nullptr, bd1, o);
}

// Round 29
// 121.404 us; speedup vs baseline: 1.0578x; 1.0578x over previous
//
#include <hip/hip_runtime.h>
#include <hip/hip_fp16.h>

typedef __attribute__((ext_vector_type(8))) _Float16 half8;
typedef __attribute__((ext_vector_type(2))) _Float16 h2f;
typedef __attribute__((ext_vector_type(4))) float f32x4;

#define NP 1369
#define KP 1376          /* padded row stride: 43 tiles of 32 */
#define NKT 43
#define ROWS_A 15360     /* 768 sbk * 20 t  */
#define ROWS_D 14592     /* 768 sbk * 19 dt */

/* ws layout (ushort units). total = 84,119,488 B <= 84.25MB proven */
#define PA_OFF   0
#define PD_OFF   (ROWS_A * KP)          /* Hraw fp32 (gemmAB); PDIG fp16 (k0->k1a, aliased) */
#define PWH_OFF  (PD_OFF + ROWS_D * KP)
#define PWD_OFF  (PWH_OFF + NKT * 16 * 512)
#define PW2_OFF  (PWD_OFF + NKT * 16 * 512)
#define PWD2_OFF (PW2_OFF + 8 * 16 * 512)
#define TSUM_OFF (PWD2_OFF + 8 * 8 * 512)   /* 768 floats */

/* k1a frame-copy layout (dwords): copy0 at 0, copy1 at 2384 (== 16 mod 32 banks) */
#define SHIFT_DW 2384

__device__ __forceinline__ unsigned short f2h(float f) {
    __half h = __float2half(f);
    return __half_as_ushort(h);
}
__device__ __forceinline__ h2f u2h2(unsigned int u) {
    h2f r; __builtin_memcpy(&r, &u, 4); return r;
}

// ============ k0: pack weights (fp16 B-frags) + tsum + PDIG template pack ============
// blocks [0,3136): weight pack; [3136,3328): tsum; [3328,3664): PDIG (digit->fp16).
__global__ __launch_bounds__(256)
void k0_pack(const float* __restrict__ w_h1, const float* __restrict__ wd1,
             const float* __restrict__ wm1,  const float* __restrict__ ws1,
             const float* __restrict__ wd2,  const float* __restrict__ digit,
             unsigned short* __restrict__ wsu, float* __restrict__ tsum)
{
    const int tid = threadIdx.x;
    if (blockIdx.x >= 3328) {            // PDIG pack: 86016 uint4s
        int g = (blockIdx.x - 3328) * 256 + tid;   // 0..86015
        int sbk = g / 112;
        int rem = g - sbk * 112;
        int kt = rem >> 2, v0g = rem & 3;
        const float* tp = digit + (size_t)sbk * 784 + kt * 28 + v0g * 8;
        float4 fa = *(const float4*)tp;
        float4 fb = (v0g < 3) ? *(const float4*)(tp + 4) : make_float4(0.f, 0.f, 0.f, 0.f);
        uint4 pk;
        pk.x = (unsigned)f2h(fa.x) | ((unsigned)f2h(fa.y) << 16);
        pk.y = (unsigned)f2h(fa.z) | ((unsigned)f2h(fa.w) << 16);
        pk.z = (unsigned)f2h(fb.x) | ((unsigned)f2h(fb.y) << 16);
        pk.w = (unsigned)f2h(fb.z) | ((unsigned)f2h(fb.w) << 16);
        *(uint4*)(wsu + PD_OFF + (size_t)g * 8) = pk;
        return;
    }
    if (blockIdx.x >= 3136) {            // tsum blocks: 4 sbk per block
        const int sbk = (blockIdx.x - 3136) * 4 + (tid >> 6);
        const int l = tid & 63;
        const float* tp = digit + (size_t)sbk * 784;
        float s = 0.f;
        for (int i = l; i < 784; i += 64) s += tp[i];
        for (int o = 32; o; o >>= 1) s += __shfl_xor(s, o, 64);
        if (l == 0) tsum[sbk] = 0.5f * s;
        return;
    }
    int idx = blockIdx.x * 256 + tid;      // 0..802815
    int local, mode;
    unsigned short* dst;
    if (idx < 352256)      { mode = 0; local = idx;          dst = wsu + PWH_OFF; }
    else if (idx < 704512) { mode = 1; local = idx - 352256; dst = wsu + PWD_OFF; }
    else if (idx < 770048) { mode = 2; local = idx - 704512; dst = wsu + PW2_OFF; }
    else                   { mode = 3; local = idx - 770048; dst = wsu + PWD2_OFF; }
    int j = local & 7, lane = (local >> 3) & 63, rest = local >> 9;
    int NTn = (mode == 3) ? 8 : 16;
    int nt = rest % NTn, kt = rest / NTn;
    int k = kt * 32 + ((lane >> 4) << 3) + j;
    int n = nt * 16 + (lane & 15);
    float v = 0.f;
    if (mode == 0)      { if (k < NP) v = w_h1[k * 256 + n]; }
    else if (mode == 1) { if (k < NP) v = wd1[k * 256 + n]; }
    else if (mode == 2) { v = (n < 128) ? wm1[k * 128 + n] : ws1[k * 128 + (n - 128)]; }
    else                { v = wd2[k * 128 + n]; }
    dst[local] = f2h(v);
}

// ============ k1a: im2col MFMA correlation, N=48, 4-phase B (PDIG copy), dual frame copy ==
__global__ __launch_bounds__(512)
void k1a_corr(const float* __restrict__ frames, const float* __restrict__ digit,
              const float* __restrict__ tsum, unsigned short* __restrict__ wsu)
{
    __shared__ __align__(16) unsigned short Bs[7 * 3 * 512];   // 21,504 B; TT alias 13,056 B
    __shared__ __align__(16) unsigned int frd[SHIFT_DW + 64 * 37];  // 19,008 B
    __shared__ float Cn[48];

    const int tid = threadIdx.x, l = tid & 63, w = tid >> 6;
    const int mh = blockIdx.x & 1;
    const int bt = blockIdx.x >> 1;
    const int t  = bt % 20;
    const int bb = bt / 20;
    const unsigned short* pdig = wsu + PD_OFF;

    if (tid < 48) {
        int sbk_n = ((tid / 3) * 16 + bb) * 3 + (tid % 3);
        Cn[tid] = tsum[sbk_n];
    }
    if (tid < 320) {   // zero pad dwords 32..36 of both copies
        int r = tid / 5, d2 = tid - r * 5;
        frd[r * 37 + 32 + d2] = 0u;
        frd[SHIFT_DW + r * 37 + 32 + d2] = 0u;
    }
    {   // stage aligned fp16-pair copy (scalar dword stores; odd stride)
        const float4* fp4 = (const float4*)(frames + (size_t)(bb * 20 + t) * 4096);
        for (int idx = tid; idx < 1024; idx += 512) {
            float4 v = fp4[idx];
            int r = idx >> 4, c4 = idx & 15;
            unsigned lo = (unsigned)f2h(v.x) | ((unsigned)f2h(v.y) << 16);
            unsigned hi = (unsigned)f2h(v.z) | ((unsigned)f2h(v.w) << 16);
            frd[r * 37 + c4 * 2]     = lo;
            frd[r * 37 + c4 * 2 + 1] = hi;
        }
    }
    __syncthreads();
    // build shifted copy: dword d holds halfs (2d+1, 2d+2)
    for (int i = tid; i < 64 * 34; i += 512) {
        int r = i / 34, d = i - r * 34;
        unsigned lo = frd[r * 37 + d], hi = frd[r * 37 + d + 1];
        frd[SHIFT_DW + r * 37 + d] = (lo >> 16) | (hi << 16);
    }

    const int c15 = l & 15, quad = l >> 4, v0q = quad << 3;
    const int cnt = (50 - w) / 8;        // waves 0-2: 6 tiles, 3-7: 5 tiles (43 total)

    int baseb[6];
#pragma unroll
    for (int it = 0; it < 6; ++it) {
        int tI = mh * 43 + w + 8 * it;
        int p  = tI * 16 + c15;
        int pc = p > 1368 ? 1368 : p;
        int i  = pc / 37;
        int jj = pc - i * 37;
        int c  = jj + v0q;
        baseb[it] = (c & 1) * (SHIFT_DW * 4) + i * 148 + ((c >> 1) << 2);   // byte offset
    }
    f32x4 acc[6][3];
#pragma unroll
    for (int it = 0; it < 6; ++it)
#pragma unroll
        for (int nt = 0; nt < 3; ++nt) acc[it][nt] = (f32x4){0.f, 0.f, 0.f, 0.f};

    for (int ph = 0; ph < 4; ++ph) {
        __syncthreads();   // frd ready (ph0); Bs consumers done (ph>0)
        // ---- stage B for kt = ph*7 .. ph*7+6 (uint4 copy from PDIG) ----
        for (int s = tid; s < 1344; s += 512) {
            int ktl = s / 192;
            int rem = s - ktl * 192;
            int nt = rem >> 6, sl = rem & 63;
            int nl = nt * 16 + (sl & 15);
            int kt = ph * 7 + ktl;
            int sbk_n = ((nl / 3) * 16 + bb) * 3 + (nl % 3);
            uint4 pk = *(const uint4*)(pdig + (size_t)sbk_n * 896 + kt * 32 + (sl >> 4) * 8);
            *(uint4*)(Bs + s * 8) = pk;
        }
        __syncthreads();

        for (int ktl = 0; ktl < 7; ++ktl) {
            const int kt = ph * 7 + ktl;
            half8 bf0 = *(const half8*)(Bs + ktl * 1536 + 0 * 512 + l * 8);
            half8 bf1 = *(const half8*)(Bs + ktl * 1536 + 1 * 512 + l * 8);
            half8 bf2 = *(const half8*)(Bs + ktl * 1536 + 2 * 512 + l * 8);
            const char* fb2 = (const char*)frd + (size_t)kt * 148;
#pragma unroll
            for (int it = 0; it < 6; ++it) {
                if (it < cnt) {
                    const unsigned* ap = (const unsigned*)(fb2 + baseb[it]);
                    union { unsigned u[4]; half8 h8; } af;
                    af.u[0] = ap[0];
                    af.u[1] = ap[1];
                    af.u[2] = ap[2];
                    af.u[3] = ap[3];
                    acc[it][0] = __builtin_amdgcn_mfma_f32_16x16x32_f16(af.h8, bf0, acc[it][0], 0, 0, 0);
                    acc[it][1] = __builtin_amdgcn_mfma_f32_16x16x32_f16(af.h8, bf1, acc[it][1], 0, 0, 0);
                    acc[it][2] = __builtin_amdgcn_mfma_f32_16x16x32_f16(af.h8, bf2, acc[it][2], 0, 0, 0);
                }
            }
        }
    }

    // ---- epilogue: per it-group, LDS transpose (TT=Bs alias) -> coalesced writes ----
    for (int itg = 0; itg < 6; ++itg) {
        __syncthreads();   // previous itg copy (or main-loop Bs reads) done
        if (itg < cnt) {
#pragma unroll
            for (int nt = 0; nt < 3; ++nt) {
                const int nl = nt * 16 + c15;
                const float C = Cn[nl];
                ushort4 st;
                st.x = f2h(acc[itg][nt][0] - C);
                st.y = f2h(acc[itg][nt][1] - C);
                st.z = f2h(acc[itg][nt][2] - C);
                st.w = f2h(acc[itg][nt][3] - C);
                *(ushort4*)(Bs + nl * 136 + w * 16 + quad * 4) = st;
            }
        }
        __syncthreads();
        const int nseg = (itg == 5) ? 6 : 16;   // 8-half segments per row
        for (int i = tid; i < 48 * nseg; i += 512) {
            int rowl = i / nseg, seg = i - rowl * nseg;
            int sbk_n = ((rowl / 3) * 16 + bb) * 3 + (rowl % 3);
            uint4 v = *(const uint4*)(Bs + rowl * 136 + seg * 8);
            *(uint4*)(wsu + PA_OFF + (size_t)(sbk_n * 20 + t) * KP
                      + mh * 688 + itg * 128 + seg * 8) = v;
        }
    }
}

// ============ k2_gemmAB: merged GEMMs + stats prepass + fused heads (8-wave split) ====
__global__ __launch_bounds__(512)
void k2_gemmAB(unsigned short* __restrict__ wsu, const float* __restrict__ b_h1,
               const float* __restrict__ bm1, const float* __restrict__ bs1,
               const float* __restrict__ wm2, const float* __restrict__ bm2,
               const float* __restrict__ ws2, const float* __restrict__ bs2,
               float* __restrict__ out)
{
    __shared__ __align__(16) unsigned short Bbuf[2][2 * 8192];   // [dbuf][{H,D}] 64KB
    __shared__ __align__(16) unsigned short Hs[64 * 264];        // hidden, swizzled, 33.8KB
    __shared__ float2 smstats[64];

    const int tid = threadIdx.x, l = tid & 63, w = tid >> 6;
    const int c15 = l & 15, quad = l >> 4;
    const int M0 = blockIdx.x * 64;
    unsigned short* Abase = wsu + PA_OFF;
    const unsigned short* PWH = wsu + PWH_OFF;
    const unsigned short* PWD = wsu + PWD_OFF;
    float* HR = (float*)(wsu + PD_OFF);

    const bool isH = (w < 4);
    const int wl = w & 3;
    const int row0 = M0 + wl * 16 + c15;
    const unsigned short* a0p = Abase + (size_t)row0 * KP + quad * 8;

    // ---- stats prepass: wave w handles local rows w*8 .. w*8+7 ----
    for (int rr = 0; rr < 8; ++rr) {
        const int lrow = w * 8 + rr;
        const unsigned* rp = (const unsigned*)(Abase + (size_t)(M0 + lrow) * KP);
        float f0[11], f1[11];
        float mx = -3.0e38f;
#pragma unroll
        for (int i = 0; i < 11; ++i) {
            int q = l + i * 64;
            unsigned u = (q < 685) ? rp[q] : 0u;
            h2f h = u2h2(u);
            f0[i] = (q < 685) ? (float)h[0] : -3.0e38f;
            f1[i] = (q < 684) ? (float)h[1] : -3.0e38f;   // half 1369 is pad
            mx = fmaxf(mx, fmaxf(f0[i], f1[i]));
        }
        for (int o = 32; o; o >>= 1) mx = fmaxf(mx, __shfl_xor(mx, o, 64));
        float sum = 0.f;
#pragma unroll
        for (int i = 0; i < 11; ++i)
            sum += __expf(f0[i] - mx) + __expf(f1[i] - mx);
        for (int o = 32; o; o >>= 1) sum += __shfl_xor(sum, o, 64);
        if (l == 0) smstats[lrow] = make_float2(mx, 1.0f / sum);
    }

    f32x4 acc[16];
#pragma unroll
    for (int n = 0; n < 16; ++n) acc[n] = (f32x4){0.f, 0.f, 0.f, 0.f};

    // prologue: stage B(0) -> buf0; load A(0)
    {
        const int4* sH = (const int4*)(PWH);
        const int4* sD = (const int4*)(PWD);
        int4* dH = (int4*)(Bbuf[0]);
        int4* dD = (int4*)(Bbuf[0] + 8192);
#pragma unroll
        for (int c = 0; c < 2; ++c) {
            dH[tid + 512 * c] = sH[tid + 512 * c];
            dD[tid + 512 * c] = sD[tid + 512 * c];
        }
    }
    half8 curA = *(const half8*)(a0p);
    __syncthreads();   // smstats + Bbuf[0] ready

    float2 st0 = make_float2(0.f, 0.f);
    if (isH) st0 = smstats[wl * 16 + c15];

    for (int kt = 0; kt < NKT; ++kt) {
        const int db = kt & 1;
        half8 nxtA = curA;
        if (kt + 1 < NKT) nxtA = *(const half8*)(a0p + (kt + 1) * 32);
        int4 rH[2], rD[2];
        if (kt + 1 < NKT) {
            const int4* sH = (const int4*)(PWH + (size_t)(kt + 1) * 8192);
            const int4* sD = (const int4*)(PWD + (size_t)(kt + 1) * 8192);
#pragma unroll
            for (int c = 0; c < 2; ++c) {
                rH[c] = sH[tid + 512 * c];
                rD[c] = sD[tid + 512 * c];
            }
        }
        half8 af = curA;
        if (isH) {
            union { half8 h8; unsigned u[4]; } ia, oa;
            ia.h8 = af;
#pragma unroll
            for (int q = 0; q < 4; ++q) {
                h2f ha = u2h2(ia.u[q]);
                float a0 = __expf((float)ha[0] - st0.x) * st0.y;
                float a1 = __expf((float)ha[1] - st0.x) * st0.y;
                oa.u[q] = (unsigned)f2h(a0) | ((unsigned)f2h(a1) << 16);
            }
            af = oa.h8;
        }
        const unsigned short* bb = Bbuf[db] + (isH ? 0 : 8192);
#pragma unroll
        for (int nt = 0; nt < 16; ++nt) {
            half8 bf = *(const half8*)(bb + nt * 512 + l * 8);
            acc[nt] = __builtin_amdgcn_mfma_f32_16x16x32_f16(af, bf, acc[nt], 0, 0, 0);
        }
        if (kt + 1 < NKT) {
            int4* dH = (int4*)(Bbuf[db ^ 1]);
            int4* dD = (int4*)(Bbuf[db ^ 1] + 8192);
#pragma unroll
            for (int c = 0; c < 2; ++c) {
                dH[tid + 512 * c] = rH[c];
                dD[tid + 512 * c] = rD[c];
            }
        }
        curA = nxtA;
        __syncthreads();
    }

    // ---- epilogue: H -> hidden in LDS (swizzled); D -> Hraw global ----
    if (isH) {
#pragma unroll
        for (int nt = 0; nt < 16; ++nt) {
            const int col = nt * 16 + c15;
            const float bv = b_h1[col];
#pragma unroll
            for (int r = 0; r < 4; ++r) {
                const int lrow = wl * 16 + quad * 4 + r;
                const int csw = col ^ ((lrow & 7) << 3);
                float v = acc[nt][r] + bv;
                Hs[lrow * 264 + csw] = f2h(v > 0.f ? v : 0.f);
            }
        }
    } else {
#pragma unroll
        for (int nt = 0; nt < 16; ++nt) {
            const int col = nt * 16 + c15;
#pragma unroll
            for (int r = 0; r < 4; ++r) {
                const int row = M0 + wl * 16 + quad * 4 + r;
                HR[(size_t)row * 256 + col] = acc[nt][r];
            }
        }
    }
    __syncthreads();   // Hs visible to head phase

    // ===== fused heads: all 8 waves. nh = w>>2 selects mean (0) / std (1) half =====
    const unsigned short* PW2 = wsu + PW2_OFF;
    const int nh = w >> 2;
    {
        const int4* src = (const int4*)(PW2);
        int4* dst = (int4*)(Bbuf[0]);
#pragma unroll
        for (int cc = 0; cc < 2; ++cc) dst[tid + 512 * cc] = src[tid + 512 * cc];
    }
    __syncthreads();

    f32x4 acc2[8];
#pragma unroll
    for (int n = 0; n < 8; ++n) acc2[n] = (f32x4){0.f, 0.f, 0.f, 0.f};

    const int hr0 = wl * 16 + c15;
    for (int kt = 0; kt < 8; ++kt) {
        const int db = kt & 1;
        int4 rB2[2];
        if (kt + 1 < 8) {
            const int4* src = (const int4*)(PW2 + (size_t)(kt + 1) * 8192);
#pragma unroll
            for (int cc = 0; cc < 2; ++cc) rB2[cc] = src[tid + 512 * cc];
        }
        {
            const int hoff = (kt * 32 + quad * 8) ^ ((hr0 & 7) << 3);
            half8 af2 = *(const half8*)(Hs + hr0 * 264 + hoff);
#pragma unroll
            for (int nt = 0; nt < 8; ++nt) {
                half8 bf = *(const half8*)(Bbuf[db] + (nh * 8 + nt) * 512 + l * 8);
                acc2[nt] = __builtin_amdgcn_mfma_f32_16x16x32_f16(af2, bf, acc2[nt], 0, 0, 0);
            }
        }
        if (kt + 1 < 8) {
            int4* dst = (int4*)(Bbuf[db ^ 1]);
#pragma unroll
            for (int cc = 0; cc < 2; ++cc) dst[tid + 512 * cc] = rB2[cc];
        }
        __syncthreads();
    }

    {
        // bias + relu for this wave's N-half
#pragma unroll
        for (int nt = 0; nt < 8; ++nt) {
            float bv = (nh == 0) ? bm1[nt * 16 + c15] : bs1[nt * 16 + c15];
#pragma unroll
            for (int r = 0; r < 4; ++r) {
                float v = acc2[nt][r] + bv;
                acc2[nt][r] = v > 0.f ? v : 0.f;
            }
        }
        const float* w2 = (nh == 0) ? wm2 : ws2;
        float pp[2][4];
#pragma unroll
        for (int d = 0; d < 2; ++d)
#pragma unroll
            for (int r = 0; r < 4; ++r) pp[d][r] = 0.f;
#pragma unroll
        for (int d = 0; d < 2; ++d)
#pragma unroll
            for (int nt = 0; nt < 8; ++nt) {
                const float wv = w2[(nt * 16 + c15) * 2 + d];
#pragma unroll
                for (int r = 0; r < 4; ++r)
                    pp[d][r] = fmaf(acc2[nt][r], wv, pp[d][r]);
            }
#pragma unroll
        for (int o = 1; o < 16; o <<= 1)
#pragma unroll
            for (int d = 0; d < 2; ++d)
#pragma unroll
                for (int r = 0; r < 4; ++r)
                    pp[d][r] += __shfl_xor(pp[d][r], o, 64);
        if (c15 == 0) {
#pragma unroll
            for (int r = 0; r < 4; ++r) {
                const int orow = M0 + wl * 16 + quad * 4 + r;
                const int sbk = orow / 20, t = orow % 20;
                const int sb = sbk / 3, kk = sbk % 3;
                const int oi = ((sb * 20 + t) * 3 + kk) * 2;
                if (nh == 0) {
                    out[oi + 0] = tanhf(pp[0][r] + bm2[0]);
                    out[oi + 1] = tanhf(pp[1][r] + bm2[1]);
                } else {
                    out[30720 + oi + 0] = __expf(pp[0][r] + bs2[0]);
                    out[30720 + oi + 1] = __expf(pp[1][r] + bs2[1]);
                }
            }
        }
    }
}

// ============ k2_heads: D-path second GEMM (K=256) + disp head ============
template <bool PATHA>
__global__ __launch_bounds__(256)
void k2_heads(unsigned short* __restrict__ wsu,
              const float* __restrict__ b1a, const float* __restrict__ b1b,
              const float* __restrict__ w2a, const float* __restrict__ b2a,
              const float* __restrict__ w2b, const float* __restrict__ b2b,
              const float* __restrict__ bd1, float* __restrict__ out)
{
    constexpr int NT2 = PATHA ? 16 : 8;
    constexpr int NI4 = NT2 / 4;
    __shared__ __align__(16) unsigned short Bsh[2][NT2 * 512];
    const int tid = threadIdx.x, l = tid & 63, w = tid >> 6;
    const int c = l & 15, quad = l >> 4;
    const int M0 = blockIdx.x * 64;
    const unsigned short* PW = wsu + (PATHA ? PW2_OFF : PWD2_OFF);

    f32x4 acc[NT2];
#pragma unroll
    for (int n = 0; n < NT2; ++n) acc[n] = (f32x4){0.f, 0.f, 0.f, 0.f};

    const int row = M0 + w * 16 + c;
    const unsigned short* arow = nullptr;
    const float* h1p = nullptr; const float* h0p = nullptr;
    if (PATHA) {
        arow = wsu + PA_OFF + (size_t)row * KP + quad * 8;
    } else {
        const float* HR = (const float*)(wsu + PD_OFF);
        const int sbk = row / 19, dt = row % 19;
        h0p = HR + (size_t)(sbk * 20 + dt) * 256 + quad * 8;
        h1p = h0p + 256;
    }

    {
        const int4* src = (const int4*)(PW);
        int4* dst = (int4*)Bsh[0];
#pragma unroll
        for (int cc = 0; cc < NI4; ++cc)
            dst[tid + 256 * cc] = src[tid + 256 * cc];
    }
    half8 curPA = {};
    float4 c1a = {}, c1b = {}, c0a = {}, c0b = {};
    if (PATHA) {
        curPA = *(const half8*)(arow);
    } else {
        c1a = *(const float4*)(h1p); c1b = *(const float4*)(h1p + 4);
        c0a = *(const float4*)(h0p); c0b = *(const float4*)(h0p + 4);
    }
    __syncthreads();

    for (int kt = 0; kt < 8; ++kt) {
        const int db = kt & 1;
        half8 nxtPA = curPA;
        float4 n1a = c1a, n1b = c1b, n0a = c0a, n0b = c0b;
        if (kt + 1 < 8) {
            if (PATHA) {
                nxtPA = *(const half8*)(arow + (kt + 1) * 32);
            } else {
                n1a = *(const float4*)(h1p + (kt + 1) * 32);
                n1b = *(const float4*)(h1p + (kt + 1) * 32 + 4);
                n0a = *(const float4*)(h0p + (kt + 1) * 32);
                n0b = *(const float4*)(h0p + (kt + 1) * 32 + 4);
            }
        }
        int4 rB[NI4];
        if (kt + 1 < 8) {
            const int4* src = (const int4*)(PW + (size_t)(kt + 1) * (NT2 * 512));
#pragma unroll
            for (int cc = 0; cc < NI4; ++cc) rB[cc] = src[tid + 256 * cc];
        }
        half8 af;
        if (PATHA) {
            af = curPA;
        } else {
            float4 bb = *(const float4*)(bd1 + kt * 32 + quad * 8);
            float4 bb2 = *(const float4*)(bd1 + kt * 32 + quad * 8 + 4);
            float v0 = fmaxf(c1a.x - c0a.x + bb.x, 0.f);
            float v1 = fmaxf(c1a.y - c0a.y + bb.y, 0.f);
            float v2 = fmaxf(c1a.z - c0a.z + bb.z, 0.f);
            float v3 = fmaxf(c1a.w - c0a.w + bb.w, 0.f);
            float v4 = fmaxf(c1b.x - c0b.x + bb2.x, 0.f);
            float v5 = fmaxf(c1b.y - c0b.y + bb2.y, 0.f);
            float v6 = fmaxf(c1b.z - c0b.z + bb2.z, 0.f);
            float v7 = fmaxf(c1b.w - c0b.w + bb2.w, 0.f);
            union { unsigned u[4]; half8 h8; } pk;
            pk.u[0] = (unsigned)f2h(v0) | ((unsigned)f2h(v1) << 16);
            pk.u[1] = (unsigned)f2h(v2) | ((unsigned)f2h(v3) << 16);
            pk.u[2] = (unsigned)f2h(v4) | ((unsigned)f2h(v5) << 16);
            pk.u[3] = (unsigned)f2h(v6) | ((unsigned)f2h(v7) << 16);
            af = pk.h8;
        }
#pragma unroll
        for (int nt = 0; nt < NT2; ++nt) {
            half8 bf = *(const half8*)(Bsh[db] + nt * 512 + l * 8);
            acc[nt] = __builtin_amdgcn_mfma_f32_16x16x32_f16(af, bf, acc[nt], 0, 0, 0);
        }
        if (kt + 1 < 8) {
            int4* dst = (int4*)Bsh[db ^ 1];
#pragma unroll
            for (int cc = 0; cc < NI4; ++cc) dst[tid + 256 * cc] = rB[cc];
        }
        curPA = nxtPA;
        c1a = n1a; c1b = n1b; c0a = n0a; c0b = n0b;
        __syncthreads();
    }
#pragma unroll
    for (int nt = 0; nt < NT2; ++nt) {
        float bv;
        if (PATHA) bv = (nt < 8) ? b1a[nt * 16 + c] : b1b[(nt - 8) * 16 + c];
        else       bv = b1a[nt * 16 + c];
#pragma unroll
        for (int r = 0; r < 4; ++r) {
            float v = acc[nt][r] + bv;
            acc[nt][r] = v > 0.f ? v : 0.f;
        }
    }
    float pm[2][4], ps[2][4];
#pragma unroll
    for (int d = 0; d < 2; ++d)
#pragma unroll
        for (int r = 0; r < 4; ++r) { pm[d][r] = 0.f; ps[d][r] = 0.f; }
#pragma unroll
    for (int d = 0; d < 2; ++d)
#pragma unroll
        for (int nt = 0; nt < 8; ++nt) {
            const float wmv = w2a[(nt * 16 + c) * 2 + d];
            float wsv = 0.f;
            if (PATHA) wsv = w2b[(nt * 16 + c) * 2 + d];
#pragma unroll
            for (int r = 0; r < 4; ++r) {
                pm[d][r] = fmaf(acc[nt][r], wmv, pm[d][r]);
                if (PATHA) ps[d][r] = fmaf(acc[nt + 8][r], wsv, ps[d][r]);
            }
        }
#pragma unroll
    for (int o = 1; o < 16; o <<= 1)
#pragma unroll
        for (int d = 0; d < 2; ++d)
#pragma unroll
            for (int r = 0; r < 4; ++r) {
                pm[d][r] += __shfl_xor(pm[d][r], o, 64);
                if (PATHA) ps[d][r] += __shfl_xor(ps[d][r], o, 64);
            }
    if (c == 0) {
#pragma unroll
        for (int r = 0; r < 4; ++r) {
            const int orow = M0 + w * 16 + quad * 4 + r;
            if (PATHA) {
                const int sbk = orow / 20, t = orow % 20;
                const int sb = sbk / 3, kk = sbk % 3;
                const int oi = ((sb * 20 + t) * 3 + kk) * 2;
                out[oi + 0] = tanhf(pm[0][r] + b2a[0]);
                out[oi + 1] = tanhf(pm[1][r] + b2a[1]);
                out[30720 + oi + 0] = __expf(ps[0][r] + b2b[0]);
                out[30720 + oi + 1] = __expf(ps[1][r] + b2b[1]);
            } else {
                const int sbk = orow / 19, dt = orow % 19;
                const int sb = sbk / 3, kk = sbk % 3;
                const int oi = 61440 + ((sb * 19 + dt) * 3 + kk) * 2;
                out[oi + 0] = tanhf(pm[0][r] + b2a[0]);
                out[oi + 1] = tanhf(pm[1][r] + b2a[1]);
            }
        }
    }
}

extern "C" void kernel_launch(void* const* d_in, const int* in_sizes, int n_in,
                              void* d_out, int out_size, void* d_ws, size_t ws_size,
                              hipStream_t stream) {
    const float* frames = (const float*)d_in[0];
    const float* digit  = (const float*)d_in[1];
    const float* w_h1   = (const float*)d_in[2];
    const float* b_h1   = (const float*)d_in[3];
    const float* wm1    = (const float*)d_in[4];
    const float* bm1    = (const float*)d_in[5];
    const float* wm2    = (const float*)d_in[6];
    const float* bm2    = (const float*)d_in[7];
    const float* ws1    = (const float*)d_in[8];
    const float* bs1    = (const float*)d_in[9];
    const float* ws2    = (const float*)d_in[10];
    const float* bs2    = (const float*)d_in[11];
    const float* wd1    = (const float*)d_in[12];
    const float* bd1    = (const float*)d_in[13];
    const float* wd2    = (const float*)d_in[14];
    const float* bd2    = (const float*)d_in[15];
    const float* wd3    = (const float*)d_in[16];
    const float* bd3    = (const float*)d_in[17];

    unsigned short* wsu = (unsigned short*)d_ws;
    float* tsum = (float*)(wsu + TSUM_OFF);
    float* o = (float*)d_out;

    k0_pack<<<dim3(3664), dim3(256), 0, stream>>>(w_h1, wd1, wm1, ws1, wd2, digit, wsu, tsum);
    k1a_corr<<<dim3(640), dim3(512), 0, stream>>>(frames, digit, tsum, wsu);
    k2_gemmAB<<<dim3(240), dim3(512), 0, stream>>>(wsu, b_h1, bm1, bs1, wm2, bm2, ws2, bs2, o);
    k2_heads<false><<<dim3(228), dim3(256), 0, stream>>>(wsu, bd2, nullptr, wd3, bd3, nullptr, nullptr, bd1, o);
}